// Round 6
// baseline (1269.651 us; speedup 1.0000x reference)
//
#include <hip/hip_runtime.h>

// ---------------------------------------------------------------------------
// VGAE encoder, MI355X. The two adj (16384x16384 f32, 1 GiB) GEMMs dominate.
// fp32 has no MFMA on CDNA4 -> split f32 into bf16 hi+lo, 3 MFMA terms
// (hi*hi + hi*lo + lo*hi), fp32 accumulate. Floor = 2 adj passes ~340us.
// R2: counted-vmcnt barriers + reg rings.                (796us)
// R3: deeper B prefetch, nontemporal adj.                (783us, flat)
// R4: 2 blocks/CU TLP.                                   (817us, worse)
// R5: K=256 macro LDS staging, 1KB adj bursts.           (724us, +8%)
// R6: B-traffic theory: B frags were 4.3GB/dispatch through L1/L2 (4x the
// adj stream). Double M-tile to 128x128 + K-split-2 (grid stays 256 = 1
// block/CU): B traffic halves, adj unchanged. Partials P0+P1 reduced in
// the consumers (relu fused into S3 producer; sum fused into final).
// ---------------------------------------------------------------------------

typedef __bf16 bf16_t;
typedef __attribute__((ext_vector_type(2))) __bf16 bf16x2;
typedef __attribute__((ext_vector_type(8))) __bf16 bf16x8;
typedef __attribute__((ext_vector_type(16))) float f32x16;
typedef __attribute__((ext_vector_type(2)))  float f32x2;

#define N_NODES 16384

// Fragment layout for the B operand of mfma_f32_32x32x16_bf16:
// element (k=r, col=c) -> 1KiB units indexed by (K16 = r>>4, cblk = c>>5),
// within a unit: lane = (c&31) + 32*((r>>3)&1) holds 8 bf16 (k = ..8g..8g+7).
__device__ __forceinline__ int frag_off(int r, int c) {
    int K16  = r >> 4;
    int cblk = c >> 5;
    int g    = (r >> 3) & 1;
    int lane = (c & 31) + (g << 5);
    return ((K16 * 4 + cblk) << 9) + (lane << 3) + (r & 7);
}

__device__ __forceinline__ float4 relu_add4(float4 a, float4 b) {
    float4 r;
    r.x = fmaxf(a.x + b.x, 0.f); r.y = fmaxf(a.y + b.y, 0.f);
    r.z = fmaxf(a.z + b.z, 0.f); r.w = fmaxf(a.w + b.w, 0.f);
    return r;
}

// ---------------------------------------------------------------------------
// Small fp32 GEMM producer: out = A[16384][K] @ W[K][128]; epilogue splits
// each output into bf16 hi/lo and scatters into the fragment layout.
// ADD2: A := relu(A + A2) elementwise (fused partial-reduce of the hidden).
// ---------------------------------------------------------------------------
template<int K, bool FUSED, bool ADD2>
__global__ __launch_bounds__(256)
void producer_kernel(const float* __restrict__ A,
                     const float* __restrict__ A2,
                     const float* __restrict__ W,
                     const float* __restrict__ Wa,
                     const float* __restrict__ Wb,
                     bf16_t* __restrict__ Bh,
                     bf16_t* __restrict__ Bl)
{
    __shared__ float As[32][128];   // k-major A tile: As[k][r]
    __shared__ float Wsh[32][128];  // Wsh[k][c]
    const int t    = threadIdx.x;
    const int row0 = blockIdx.x * 128;
    const int tc   = t & 15, tr = t >> 4;   // 16x16 thread grid, 8x8 outs each

    float acc[8][8];
    #pragma unroll
    for (int i = 0; i < 8; ++i)
        #pragma unroll
        for (int j = 0; j < 8; ++j) acc[i][j] = 0.f;

    const int ra = t >> 1, ks = (t & 1) << 4;   // A staging: 16 f32/thread
    const int wk = t >> 3, wc = (t & 7) << 4;   // W staging: 16 f32/thread

    for (int k0 = 0; k0 < K; k0 += 32) {
        const float* ap = A + (size_t)(row0 + ra) * K + k0 + ks;
        float4 a0 = *(const float4*)(ap);
        float4 a1 = *(const float4*)(ap + 4);
        float4 a2 = *(const float4*)(ap + 8);
        float4 a3 = *(const float4*)(ap + 12);
        if (ADD2) {
            const float* ap2 = A2 + (size_t)(row0 + ra) * K + k0 + ks;
            a0 = relu_add4(a0, *(const float4*)(ap2));
            a1 = relu_add4(a1, *(const float4*)(ap2 + 4));
            a2 = relu_add4(a2, *(const float4*)(ap2 + 8));
            a3 = relu_add4(a3, *(const float4*)(ap2 + 12));
        }
        float4 w0, w1, w2, w3;
        if (!FUSED) {
            const float* wp = W + (size_t)(k0 + wk) * 128 + wc;
            w0 = *(const float4*)(wp);     w1 = *(const float4*)(wp + 4);
            w2 = *(const float4*)(wp + 8); w3 = *(const float4*)(wp + 12);
        } else {
            const float* wp = (wc < 64) ? (Wa + (size_t)(k0 + wk) * 64 + wc)
                                        : (Wb + (size_t)(k0 + wk) * 64 + (wc - 64));
            w0 = *(const float4*)(wp);     w1 = *(const float4*)(wp + 4);
            w2 = *(const float4*)(wp + 8); w3 = *(const float4*)(wp + 12);
        }
        __syncthreads();   // previous iteration's compute done before overwrite
        {
            float tmp[16] = {a0.x,a0.y,a0.z,a0.w, a1.x,a1.y,a1.z,a1.w,
                             a2.x,a2.y,a2.z,a2.w, a3.x,a3.y,a3.z,a3.w};
            #pragma unroll
            for (int j = 0; j < 16; ++j) As[ks + j][ra] = tmp[j];
            *(float4*)&Wsh[wk][wc     ] = w0;
            *(float4*)&Wsh[wk][wc +  4] = w1;
            *(float4*)&Wsh[wk][wc +  8] = w2;
            *(float4*)&Wsh[wk][wc + 12] = w3;
        }
        __syncthreads();
        #pragma unroll 4
        for (int k = 0; k < 32; ++k) {
            float av[8], wv[8];
            *(float4*)&av[0] = *(const float4*)&As[k][8 * tr];
            *(float4*)&av[4] = *(const float4*)&As[k][8 * tr + 4];
            *(float4*)&wv[0] = *(const float4*)&Wsh[k][8 * tc];
            *(float4*)&wv[4] = *(const float4*)&Wsh[k][8 * tc + 4];
            #pragma unroll
            for (int i = 0; i < 8; ++i)
                #pragma unroll
                for (int j = 0; j < 8; ++j)
                    acc[i][j] = fmaf(av[i], wv[j], acc[i][j]);
        }
    }

    #pragma unroll
    for (int i = 0; i < 8; ++i) {
        int r = row0 + 8 * tr + i;
        #pragma unroll
        for (int j = 0; j < 8; ++j) {
            int c = 8 * tc + j;
            float v = acc[i][j];
            bf16_t h = (bf16_t)v;
            bf16_t l = (bf16_t)(v - (float)h);
            int off = frag_off(r, c);
            Bh[off] = h;
            Bl[off] = l;
        }
    }
}

// ---------------------------------------------------------------------------
// Big kernel: partial = adj[mt-tile][kh-half] @ B[kh-half], M-tile 128,
// K-half 8192. grid 256 (128 mt x 2 kh) = 1 block/CU, 512 thr (8 waves).
// Waves: 2 row-halves x 4 col-quadrants; each wave two 32x32 tiles (rows
// +0/+32 of its 64-row band). Macro K=128: LDS [2][128][128] hi+lo (128KB),
// adj staged 16 rows/wave as 512B bursts; B frags L2->reg, 4 sets, 1-macro
// lead; one lgkmcnt-only barrier per macro (counted vmcnt across it).
// ---------------------------------------------------------------------------
struct BSet { bf16x8 h[4]; bf16x8 l[4]; };

__global__ __launch_bounds__(512, 2)
void adj_gemm_kernel(const float* __restrict__ adj,
                     const bf16_t* __restrict__ Bh,
                     const bf16_t* __restrict__ Bl,
                     float* __restrict__ P0,
                     float* __restrict__ P1)
{
    __shared__ __align__(16) bf16_t AsH[2][128 * 128];
    __shared__ __align__(16) bf16_t AsL[2][128 * 128];
    const int t    = threadIdx.x;
    const int lane = t & 63;
    const int w    = t >> 6;
    const int wr   = w >> 2, wc = w & 3;     // 2 row-halves x 4 col-quadrants
    const int mt   = blockIdx.x >> 1;
    const int kh   = blockIdx.x & 1;
    const int row0 = mt << 7;
    float* const outP = kh ? P1 : P0;

    // adj staging: wave w stages rows w*16..+15; lane covers f32x2 at k=lane*2
    const float* aBase = adj + (size_t)(row0 + (w << 4)) * 16384
                             + ((size_t)kh << 13) + (lane << 1);

    // A-frag read coords: two row-tiles frow0, frow0+32
    const int frow0 = (wr << 6) + (lane & 31);
    const int fg    = (lane >> 5) << 3;
    const int sw    = (frow0 & 15) << 3;      // (frow+32)&15 == frow&15
    const int rb0   = frow0 << 7;
    const int rb1   = (frow0 + 32) << 7;

    // B frag per-thread base (bf16 elems); sub(K=64) stride = 8192 elems
    const int tb   = (wc << 9) + (lane << 3);
    const int khs  = kh << 7;                 // kh*128 subs offset

    f32x16 acc0, acc1;
    #pragma unroll
    for (int i = 0; i < 16; ++i) { acc0[i] = 0.f; acc1[i] = 0.f; }

    f32x2 ar[16];   // one macro (16 rows x f32x2) adj prefetch

    auto loadAdj = [&](int mac) {
        const float* p = aBase + (mac << 7);
        #pragma unroll
        for (int j = 0; j < 16; ++j)
            ar[j] = __builtin_nontemporal_load((const f32x2*)(p + (size_t)j * 16384));
    };
    auto cvtWrite = [&](int buf) {
        bf16_t* const H = buf ? &AsH[1][0] : &AsH[0][0];
        bf16_t* const L = buf ? &AsL[1][0] : &AsL[0][0];
        #pragma unroll
        for (int j = 0; j < 16; ++j) {
            const int r = (w << 4) + j;
            const int idx = (r << 7) + ((lane << 1) ^ (j << 3));
            float v0 = ar[j][0], v1 = ar[j][1];
            bf16_t h0 = (bf16_t)v0, h1 = (bf16_t)v1;
            bf16x2 hv = {h0, h1};
            bf16x2 lv = {(bf16_t)(v0 - (float)h0), (bf16_t)(v1 - (float)h1)};
            *(bf16x2*)&H[idx] = hv;
            *(bf16x2*)&L[idx] = lv;
        }
    };
    auto loadB = [&](BSet& S, int sub) {
        const size_t base = ((size_t)(khs + sub) << 13) + tb;
        #pragma unroll
        for (int s = 0; s < 4; ++s) {
            S.h[s] = *(const bf16x8*)(Bh + base + (s << 11));
            S.l[s] = *(const bf16x8*)(Bl + base + (s << 11));
        }
    };
    auto computeHalf = [&](int buf, const BSet& S, int half) {
        const bf16_t* const H = buf ? &AsH[1][0] : &AsH[0][0];
        const bf16_t* const L = buf ? &AsL[1][0] : &AsL[0][0];
        #pragma unroll
        for (int s = 0; s < 4; ++s) {
            const int o = ((((half << 2) + s) << 4) + fg) ^ sw;
            bf16x8 ah0 = *(const bf16x8*)&H[rb0 + o];
            bf16x8 al0 = *(const bf16x8*)&L[rb0 + o];
            bf16x8 ah1 = *(const bf16x8*)&H[rb1 + o];
            bf16x8 al1 = *(const bf16x8*)&L[rb1 + o];
            acc0 = __builtin_amdgcn_mfma_f32_32x32x16_bf16(ah0, S.h[s], acc0, 0, 0, 0);
            acc0 = __builtin_amdgcn_mfma_f32_32x32x16_bf16(ah0, S.l[s], acc0, 0, 0, 0);
            acc0 = __builtin_amdgcn_mfma_f32_32x32x16_bf16(al0, S.h[s], acc0, 0, 0, 0);
            acc1 = __builtin_amdgcn_mfma_f32_32x32x16_bf16(ah1, S.h[s], acc1, 0, 0, 0);
            acc1 = __builtin_amdgcn_mfma_f32_32x32x16_bf16(ah1, S.l[s], acc1, 0, 0, 0);
            acc1 = __builtin_amdgcn_mfma_f32_32x32x16_bf16(al1, S.h[s], acc1, 0, 0, 0);
        }
    };

#define SYNC_LDS() do { asm volatile("s_waitcnt lgkmcnt(0)" ::: "memory"); \
                        __builtin_amdgcn_s_barrier(); } while (0)

    BSet S0, S1, S2, S3;

    // -------- prologue --------
    loadAdj(0);
    loadB(S0, 0);
    loadB(S1, 1);
    cvtWrite(0);            // waits adj(0) only (issued first, in-order)
    SYNC_LDS();
    loadAdj(1);

    // 64 macros of K=128 (per-block K = 8192). Macro m: buf = m&1, subs
    // 2m,2m+1. B loaded one macro ahead; adj two macros ahead.
    for (int m = 0; m < 62; m += 2) {
        // macro m (buf 0): S0=B(2m), S1=B(2m+1)
        loadB(S2, 2 * m + 2);
        computeHalf(0, S0, 0);
        loadB(S3, 2 * m + 3);
        computeHalf(0, S1, 1);
        cvtWrite(1);                     // adj(m+1), issued one macro ago
        SYNC_LDS();
        loadAdj(m + 2);
        // macro m+1 (buf 1): S2=B(2m+2), S3=B(2m+3)
        loadB(S0, 2 * m + 4);
        computeHalf(1, S2, 0);
        loadB(S1, 2 * m + 5);
        computeHalf(1, S3, 1);
        cvtWrite(0);                     // adj(m+2)
        SYNC_LDS();
        loadAdj(m + 3);
    }
    // -------- epilogue: macros 62 (buf 0), 63 (buf 1) --------
    loadB(S2, 126);
    computeHalf(0, S0, 0);
    loadB(S3, 127);
    computeHalf(0, S1, 1);
    cvtWrite(1);                          // adj(63)
    SYNC_LDS();
    computeHalf(1, S2, 0);
    computeHalf(1, S3, 1);
#undef SYNC_LDS

    // C write: col = wc*32 + lane&31; tile rows rb + {0,32}
    const int col = (wc << 5) + (lane & 31);
    const int rw  = row0 + (wr << 6) + ((lane >> 5) << 2);
    #pragma unroll
    for (int q = 0; q < 16; ++q) {
        int r = rw + (q & 3) + ((q >> 2) << 3);
        outP[(size_t)r * 128 + col] = acc0[q];
        outP[(size_t)(r + 32) * 128 + col] = acc1[q];
    }
}

// ---------------------------------------------------------------------------
// Final: T = T0+T1 ([16384][128], Z cols 0-63 | logstd cols 64-127);
// mean = Z@Wp + bp; out = noise*exp(min(logstd,10)) + mean
// ---------------------------------------------------------------------------
__global__ __launch_bounds__(256)
void final_kernel(const float* __restrict__ T0,
                  const float* __restrict__ T1,
                  const float* __restrict__ Wp,
                  const float* __restrict__ bp,
                  const float* __restrict__ noise,
                  float* __restrict__ out)
{
    __shared__ float Wps[64][64];
    __shared__ float Ts[64][64];
    const int t = threadIdx.x;
    const int row0 = blockIdx.x * 64;
    {
        int k = t >> 2, c0 = (t & 3) << 4;
        #pragma unroll
        for (int i = 0; i < 4; ++i)
            *(float4*)&Wps[k][c0 + 4 * i] = *(const float4*)&Wp[(size_t)k * 64 + c0 + 4 * i];
        #pragma unroll
        for (int i = 0; i < 4; ++i) {
            float4 z0 = *(const float4*)&T0[(size_t)(row0 + k) * 128 + c0 + 4 * i];
            float4 z1 = *(const float4*)&T1[(size_t)(row0 + k) * 128 + c0 + 4 * i];
            float4 zs; zs.x = z0.x + z1.x; zs.y = z0.y + z1.y;
            zs.z = z0.z + z1.z; zs.w = z0.w + z1.w;
            *(float4*)&Ts[k][c0 + 4 * i] = zs;
        }
    }
    __syncthreads();

    const int r  = t >> 2;
    const int c0 = (t & 3) << 4;
    float acc[16];
    #pragma unroll
    for (int j = 0; j < 16; ++j) acc[j] = bp[c0 + j];
    for (int k = 0; k < 64; ++k) {
        float a = Ts[r][k];
        #pragma unroll
        for (int j = 0; j < 16; ++j) acc[j] = fmaf(a, Wps[k][c0 + j], acc[j]);
    }
    const int grow = row0 + r;
    #pragma unroll
    for (int j = 0; j < 16; ++j) {
        size_t li = (size_t)grow * 128 + 64 + c0 + j;
        float ls = T0[li] + T1[li];
        ls = fminf(ls, 10.0f);
        out[(size_t)grow * 64 + c0 + j] =
            noise[(size_t)grow * 64 + c0 + j] * __expf(ls) + acc[j];
    }
}

// ---------------------------------------------------------------------------
extern "C" void kernel_launch(void* const* d_in, const int* in_sizes, int n_in,
                              void* d_out, int out_size, void* d_ws, size_t ws_size,
                              hipStream_t stream) {
    const float* X     = (const float*)d_in[0];
    const float* adj   = (const float*)d_in[1];
    const float* W1    = (const float*)d_in[2];
    const float* Wm    = (const float*)d_in[3];
    const float* Wsv   = (const float*)d_in[4];
    const float* Wp    = (const float*)d_in[5];
    const float* bp    = (const float*)d_in[6];
    const float* noise = (const float*)d_in[7];
    float* out = (float*)d_out;

    char* ws = (char*)d_ws;
    bf16_t* Bh = (bf16_t*)ws;                     // 4 MB
    bf16_t* Bl = (bf16_t*)(ws + (4u << 20));      // 4 MB
    float*  P0 = (float*)(ws + (8u << 20));       // 8 MB partial (kh=0)
    float*  P1 = (float*)(ws + (16u << 20));      // 8 MB partial (kh=1)

    // S1: B1 = fragsplit((X @ W1)^T)
    producer_kernel<256, false, false><<<128, 256, 0, stream>>>(
        X, nullptr, W1, nullptr, nullptr, Bh, Bl);
    // S2: hidden partials: P_kh = adj[:, kh-half] @ B1[kh-half]
    adj_gemm_kernel<<<256, 512, 0, stream>>>(adj, Bh, Bl, P0, P1);
    // S3: B2 = fragsplit((relu(P0+P1) @ [Wm|Ws])^T)   (reduce+relu fused)
    producer_kernel<128, true, true><<<128, 256, 0, stream>>>(
        P0, P1, nullptr, Wm, Wsv, Bh, Bl);
    // S4: T partials
    adj_gemm_kernel<<<256, 512, 0, stream>>>(adj, Bh, Bl, P0, P1);
    // S5: epilogue (T = P0+P1 summed on the fly)
    final_kernel<<<256, 256, 0, stream>>>(P0, P1, Wp, bp, noise, out);
}

// Round 7
// 1114.689 us; speedup vs baseline: 1.1390x; 1.1390x over previous
//
#include <hip/hip_runtime.h>

// ---------------------------------------------------------------------------
// VGAE encoder, MI355X. The two adj (16384x16384 f32, 1 GiB) GEMMs dominate.
// fp32 has no MFMA on CDNA4 -> split f32 into bf16 hi+lo, 3 MFMA terms
// (hi*hi + hi*lo + lo*hi), fp32 accumulate. Floor = 2 adj passes ~340us.
// R5: K=256 macro LDS staging, 1KB adj bursts.           (724us)
// R6: 128x128 + K-split2 rewrite.                        (1270us, REVERTED)
// R7: wave specialization on the R5 skeleton. Waves 0-3 = producers (pure
// adj stream: 16x 1KB bursts/macro, cvt->LDS), waves 4-7 = consumers (pure
// B stream + MFMA, 32rows x 2 col-quadrants each). Per-wave in-order vmcnt
// queues no longer mix HBM and L2 streams -> no false serialization; B
// traffic and A-LDS reads halve; 16-row swizzle kills read conflicts.
// ---------------------------------------------------------------------------

typedef __bf16 bf16_t;
typedef __attribute__((ext_vector_type(4))) __bf16 bf16x4;
typedef __attribute__((ext_vector_type(8))) __bf16 bf16x8;
typedef __attribute__((ext_vector_type(16))) float f32x16;
typedef __attribute__((ext_vector_type(4)))  float f32x4;

#define N_NODES 16384
#define MFMA3(ACC, A, B) \
    ACC = __builtin_amdgcn_mfma_f32_32x32x16_bf16(A, B, ACC, 0, 0, 0)

// Fragment layout for the B operand of mfma_f32_32x32x16_bf16:
// element (k=r, col=c) -> 1KiB units indexed by (K16 = r>>4, cblk = c>>5),
// within a unit: lane = (c&31) + 32*((r>>3)&1) holds 8 bf16 (k = ..8g..8g+7).
__device__ __forceinline__ int frag_off(int r, int c) {
    int K16  = r >> 4;
    int cblk = c >> 5;
    int g    = (r >> 3) & 1;
    int lane = (c & 31) + (g << 5);
    return ((K16 * 4 + cblk) << 9) + (lane << 3) + (r & 7);
}

// ---------------------------------------------------------------------------
// Small fp32 GEMM producer: out = A[16384][K] @ W[K][128]; epilogue splits
// each output into bf16 hi/lo and scatters into the fragment layout.
// ---------------------------------------------------------------------------
template<int K, bool FUSED>
__global__ __launch_bounds__(256)
void producer_kernel(const float* __restrict__ A,
                     const float* __restrict__ W,
                     const float* __restrict__ Wa,
                     const float* __restrict__ Wb,
                     bf16_t* __restrict__ Bh,
                     bf16_t* __restrict__ Bl)
{
    __shared__ float As[32][128];   // k-major A tile: As[k][r]
    __shared__ float Wsh[32][128];  // Wsh[k][c]
    const int t    = threadIdx.x;
    const int row0 = blockIdx.x * 128;
    const int tc   = t & 15, tr = t >> 4;   // 16x16 thread grid, 8x8 outs each

    float acc[8][8];
    #pragma unroll
    for (int i = 0; i < 8; ++i)
        #pragma unroll
        for (int j = 0; j < 8; ++j) acc[i][j] = 0.f;

    const int ra = t >> 1, ks = (t & 1) << 4;   // A staging: 16 f32/thread
    const int wk = t >> 3, wc = (t & 7) << 4;   // W staging: 16 f32/thread

    for (int k0 = 0; k0 < K; k0 += 32) {
        const float* ap = A + (size_t)(row0 + ra) * K + k0 + ks;
        float4 a0 = *(const float4*)(ap);
        float4 a1 = *(const float4*)(ap + 4);
        float4 a2 = *(const float4*)(ap + 8);
        float4 a3 = *(const float4*)(ap + 12);
        float4 w0, w1, w2, w3;
        if (!FUSED) {
            const float* wp = W + (size_t)(k0 + wk) * 128 + wc;
            w0 = *(const float4*)(wp);     w1 = *(const float4*)(wp + 4);
            w2 = *(const float4*)(wp + 8); w3 = *(const float4*)(wp + 12);
        } else {
            const float* wp = (wc < 64) ? (Wa + (size_t)(k0 + wk) * 64 + wc)
                                        : (Wb + (size_t)(k0 + wk) * 64 + (wc - 64));
            w0 = *(const float4*)(wp);     w1 = *(const float4*)(wp + 4);
            w2 = *(const float4*)(wp + 8); w3 = *(const float4*)(wp + 12);
        }
        __syncthreads();   // previous iteration's compute done before overwrite
        {
            float tmp[16] = {a0.x,a0.y,a0.z,a0.w, a1.x,a1.y,a1.z,a1.w,
                             a2.x,a2.y,a2.z,a2.w, a3.x,a3.y,a3.z,a3.w};
            #pragma unroll
            for (int j = 0; j < 16; ++j) As[ks + j][ra] = tmp[j];
            *(float4*)&Wsh[wk][wc     ] = w0;
            *(float4*)&Wsh[wk][wc +  4] = w1;
            *(float4*)&Wsh[wk][wc +  8] = w2;
            *(float4*)&Wsh[wk][wc + 12] = w3;
        }
        __syncthreads();
        #pragma unroll 4
        for (int k = 0; k < 32; ++k) {
            float av[8], wv[8];
            *(float4*)&av[0] = *(const float4*)&As[k][8 * tr];
            *(float4*)&av[4] = *(const float4*)&As[k][8 * tr + 4];
            *(float4*)&wv[0] = *(const float4*)&Wsh[k][8 * tc];
            *(float4*)&wv[4] = *(const float4*)&Wsh[k][8 * tc + 4];
            #pragma unroll
            for (int i = 0; i < 8; ++i)
                #pragma unroll
                for (int j = 0; j < 8; ++j)
                    acc[i][j] = fmaf(av[i], wv[j], acc[i][j]);
        }
    }

    #pragma unroll
    for (int i = 0; i < 8; ++i) {
        int r = row0 + 8 * tr + i;
        #pragma unroll
        for (int j = 0; j < 8; ++j) {
            int c = 8 * tc + j;
            float v = acc[i][j];
            bf16_t h = (bf16_t)v;
            bf16_t l = (bf16_t)(v - (float)h);
            int off = frag_off(r, c);
            Bh[off] = h;
            Bl[off] = l;
        }
    }
}

// ---------------------------------------------------------------------------
// Big kernel: out = act(adj @ B), M=K=16384, N=128.
// grid 256 (1 block/CU), 512 thr. WAVE-SPECIALIZED:
//   waves 0-3 (producers): adj HBM -> regs (16x 1KB bursts/macro) -> hi/lo
//     split -> swizzled LDS. Pure adj vmcnt stream.
//   waves 4-7 (consumers): B frags L2->reg (2 pairs, 1-sub lead) + MFMA.
//     Each consumer: 32 rows x 2 col-quadrants (B dedup: 2 GB total).
// Macro K=256, double-buffered LDS [2][64][256] hi+lo = 128 KB; ONE
// lgkmcnt-only barrier per macro. Swizzle: elem (r,c) at (r<<8)+(c^((r&15)<<3)).
// ---------------------------------------------------------------------------
template<int ACT>  // 0=none, 1=relu
__global__ __launch_bounds__(512)
void adj_gemm_kernel(const float* __restrict__ adj,
                     const bf16_t* __restrict__ Bh,
                     const bf16_t* __restrict__ Bl,
                     float* __restrict__ out)
{
    __shared__ __align__(16) bf16_t AsH[2][64 * 256];
    __shared__ __align__(16) bf16_t AsL[2][64 * 256];
    const int t    = threadIdx.x;
    const int lane = t & 63;
    const int w    = t >> 6;
    const bool prod = (w < 4);
    const int row0 = blockIdx.x * 64;

    // ---------------- producer state (waves 0-3) ----------------
    const int pw = w & 3;                      // stages rows pw*16..pw*16+15
    const float* aBase = adj + (size_t)(row0 + pw * 16) * 16384 + lane * 4;
    f32x4 ar[16];

    auto loadAdj = [&](int mac) {
        const float* p = aBase + ((size_t)mac << 8);
        #pragma unroll
        for (int j = 0; j < 16; ++j)
            ar[j] = __builtin_nontemporal_load((const f32x4*)(p + (size_t)j * 16384));
    };
    auto cvtWrite = [&](int buf) {
        bf16_t* const H = buf ? &AsH[1][0] : &AsH[0][0];
        bf16_t* const L = buf ? &AsL[1][0] : &AsL[0][0];
        #pragma unroll
        for (int j = 0; j < 16; ++j) {
            bf16x4 hv, lv;
            #pragma unroll
            for (int e = 0; e < 4; ++e) {
                float v = ar[j][e];
                bf16_t h = (bf16_t)v;
                hv[e] = h;
                lv[e] = (bf16_t)(v - (float)h);
            }
            const int idx = ((pw * 16 + j) << 8) + ((lane << 2) ^ (j << 3));
            *(bf16x4*)&H[idx] = hv;
            *(bf16x4*)&L[idx] = lv;
        }
    };

    // ---------------- consumer state (waves 4-7) ----------------
    const int cw   = w & 3;
    const int cwr  = cw >> 1;                  // row half (32 rows)
    const int cwc  = cw & 1;                   // col half (2 quadrants)
    const int frow = (cwr << 5) + (lane & 31);
    const int fg   = (lane >> 5) << 3;
    const int rswz = (frow & 15) << 3;
    const int rbase = frow << 8;
    const int q0   = cwc << 1;
    const int tbA  = (q0 << 9) + (lane << 3);        // quadrant q0
    const int tbB  = ((q0 + 1) << 9) + (lane << 3);  // quadrant q0+1

    f32x16 acc0, acc1;
    #pragma unroll
    for (int i = 0; i < 16; ++i) { acc0[i] = 0.f; acc1[i] = 0.f; }

    struct Pair { bf16x8 ha[4], la[4], hb[4], lb[4]; };   // 64 VGPRs
    Pair P0, P1;

    auto loadP = [&](Pair& P, int sub) {
        const size_t s0 = ((size_t)sub << 13);
        #pragma unroll
        for (int s = 0; s < 4; ++s) {
            P.ha[s] = *(const bf16x8*)(Bh + s0 + tbA + (s << 11));
            P.la[s] = *(const bf16x8*)(Bl + s0 + tbA + (s << 11));
            P.hb[s] = *(const bf16x8*)(Bh + s0 + tbB + (s << 11));
            P.lb[s] = *(const bf16x8*)(Bl + s0 + tbB + (s << 11));
        }
    };
    auto computeSub = [&](int buf, const Pair& P, int sbase) {
        const bf16_t* const H = buf ? &AsH[1][0] : &AsH[0][0];
        const bf16_t* const L = buf ? &AsL[1][0] : &AsL[0][0];
        #pragma unroll
        for (int s = 0; s < 4; ++s) {
            const int o = ((((sbase + s) << 4) + fg) ^ rswz);
            bf16x8 ah = *(const bf16x8*)&H[rbase + o];
            bf16x8 al = *(const bf16x8*)&L[rbase + o];
            MFMA3(acc0, ah, P.ha[s]);
            MFMA3(acc1, ah, P.hb[s]);
            MFMA3(acc0, ah, P.la[s]);
            MFMA3(acc1, ah, P.lb[s]);
            MFMA3(acc0, al, P.ha[s]);
            MFMA3(acc1, al, P.hb[s]);
        }
    };

    // lgkmcnt(0)-only barrier: ds ops drained; register-dest global loads
    // stay in flight across the barrier (counted vmcnt by compiler).
#define SYNC_LDS() do { asm volatile("s_waitcnt lgkmcnt(0)" ::: "memory"); \
                        __builtin_amdgcn_s_barrier(); } while (0)

    // -------- prologue --------
    if (prod) {
        loadAdj(0);
        cvtWrite(0);        // waits own adj(0) loads only
        loadAdj(1);         // ar := adj(1)
    } else {
        loadP(P0, 0);
        loadP(P1, 1);
    }
    SYNC_LDS();

    // -------- 64 macros of K=256; macro m reads buf m&1 --------
    // consumer invariant entering macro m: P0=sub(4m), P1=sub(4m+1)
    for (int m = 0; m < 63; ++m) {
        if (prod) {
            cvtWrite((m + 1) & 1);       // stage macro m+1 from ar=adj(m+1)
            if (m < 62) loadAdj(m + 2);
        } else {
            const int buf = m & 1, s4 = m << 2;
            computeSub(buf, P0, 0);   loadP(P0, s4 + 2);
            computeSub(buf, P1, 4);   loadP(P1, s4 + 3);
            computeSub(buf, P0, 8);   loadP(P0, s4 + 4);
            computeSub(buf, P1, 12);  loadP(P1, s4 + 5);
        }
        SYNC_LDS();
    }
#undef SYNC_LDS

    // -------- epilogue macro 63 (buf 1): P0=252, P1=253 --------
    if (!prod) {
        computeSub(1, P0, 0);   loadP(P0, 254);
        computeSub(1, P1, 4);   loadP(P1, 255);
        computeSub(1, P0, 8);
        computeSub(1, P1, 12);

        // C write: cols q0*32 / (q0+1)*32 + lane&31; rows per 32x32 C map
        const int col0 = (q0 << 5) + (lane & 31);
        const int rw   = row0 + (cwr << 5) + ((lane >> 5) << 2);
        #pragma unroll
        for (int q = 0; q < 16; ++q) {
            int r = rw + (q & 3) + ((q >> 2) << 3);
            float v0 = acc0[q], v1 = acc1[q];
            if (ACT == 1) { v0 = fmaxf(v0, 0.f); v1 = fmaxf(v1, 0.f); }
            out[(size_t)r * 128 + col0]      = v0;
            out[(size_t)r * 128 + col0 + 32] = v1;
        }
    }
}

// ---------------------------------------------------------------------------
// Final: mean = Z@Wp + bp; out = noise*exp(min(logstd,10)) + mean
// T = [Z | logstd] as [16384][128] f32
// ---------------------------------------------------------------------------
__global__ __launch_bounds__(256)
void final_kernel(const float* __restrict__ T,
                  const float* __restrict__ Wp,
                  const float* __restrict__ bp,
                  const float* __restrict__ noise,
                  float* __restrict__ out)
{
    __shared__ float Wps[64][64];
    __shared__ float Ts[64][64];
    const int t = threadIdx.x;
    const int row0 = blockIdx.x * 64;
    {
        int k = t >> 2, c0 = (t & 3) << 4;
        #pragma unroll
        for (int i = 0; i < 4; ++i)
            *(float4*)&Wps[k][c0 + 4 * i] = *(const float4*)&Wp[(size_t)k * 64 + c0 + 4 * i];
        #pragma unroll
        for (int i = 0; i < 4; ++i)
            *(float4*)&Ts[k][c0 + 4 * i] =
                *(const float4*)&T[(size_t)(row0 + k) * 128 + c0 + 4 * i];
    }
    __syncthreads();

    const int r  = t >> 2;
    const int c0 = (t & 3) << 4;
    float acc[16];
    #pragma unroll
    for (int j = 0; j < 16; ++j) acc[j] = bp[c0 + j];
    for (int k = 0; k < 64; ++k) {
        float a = Ts[r][k];
        #pragma unroll
        for (int j = 0; j < 16; ++j) acc[j] = fmaf(a, Wps[k][c0 + j], acc[j]);
    }
    const int grow = row0 + r;
    #pragma unroll
    for (int j = 0; j < 16; ++j) {
        float ls = T[(size_t)grow * 128 + 64 + c0 + j];
        ls = fminf(ls, 10.0f);
        out[(size_t)grow * 64 + c0 + j] =
            noise[(size_t)grow * 64 + c0 + j] * __expf(ls) + acc[j];
    }
}

// ---------------------------------------------------------------------------
extern "C" void kernel_launch(void* const* d_in, const int* in_sizes, int n_in,
                              void* d_out, int out_size, void* d_ws, size_t ws_size,
                              hipStream_t stream) {
    const float* X     = (const float*)d_in[0];
    const float* adj   = (const float*)d_in[1];
    const float* W1    = (const float*)d_in[2];
    const float* Wm    = (const float*)d_in[3];
    const float* Wsv   = (const float*)d_in[4];
    const float* Wp    = (const float*)d_in[5];
    const float* bp    = (const float*)d_in[6];
    const float* noise = (const float*)d_in[7];
    float* out = (float*)d_out;

    char* ws = (char*)d_ws;
    bf16_t* Bh   = (bf16_t*)ws;                    // 4 MB  (16384*128 bf16)
    bf16_t* Bl   = (bf16_t*)(ws + (4u << 20));     // 4 MB
    float*  Htmp = (float*)(ws + (8u << 20));      // 8 MB hidden, reused as T

    // S1: B1 = fragsplit((X @ W1)^T)
    producer_kernel<256, false><<<128, 256, 0, stream>>>(X, W1, nullptr, nullptr, Bh, Bl);
    // S2: hidden = relu(adj @ XW1)
    adj_gemm_kernel<1><<<256, 512, 0, stream>>>(adj, Bh, Bl, Htmp);
    // S3: B2 = fragsplit((hidden @ [Wm|Ws])^T)
    producer_kernel<128, true><<<128, 256, 0, stream>>>(Htmp, nullptr, Wm, Wsv, Bh, Bl);
    // S4: T = adj @ HW   (cols 0-63 = Z, 64-127 = logstd_raw)
    adj_gemm_kernel<0><<<256, 512, 0, stream>>>(adj, Bh, Bl, Htmp);
    // S5: epilogue
    final_kernel<<<256, 256, 0, stream>>>(Htmp, Wp, bp, noise, out);
}

// Round 8
// 768.289 us; speedup vs baseline: 1.6526x; 1.4509x over previous
//
#include <hip/hip_runtime.h>

// ---------------------------------------------------------------------------
// VGAE encoder, MI355X. The two adj (16384x16384 f32, 1 GiB) GEMMs dominate.
// fp32 has no MFMA on CDNA4 -> split f32 into bf16 hi+lo, 3 MFMA terms
// (hi*hi + hi*lo + lo*hi), fp32 accumulate. Floor = 2 adj passes ~340us.
// R5: K=256 macro LDS staging, 1KB adj bursts.           (724us, best)
// R6: 128x128 + K-split2 rewrite.                        (1270us, REVERTED)
// R7: producer/consumer wave split.                      (1115us, REVERTED)
// R8: R5 skeleton + strict in-order-vmcnt discipline: per macro issue
// [B(m+1) sets][adj(m+2)][compute on B(m) loaded LAST macro][cvtWrite from
// adj(m+1) issued LAST macro][lgkm-only barrier]. No wait ever drains a
// load issued <1 macro ago -> HBM latency fully hidden. Kmacro=128,
// LDS 64KB, parity-unrolled E/O B-sets + arA/arB adj rings.
// ---------------------------------------------------------------------------

typedef __bf16 bf16_t;
typedef __attribute__((ext_vector_type(4))) __bf16 bf16x4;
typedef __attribute__((ext_vector_type(8))) __bf16 bf16x8;
typedef __attribute__((ext_vector_type(16))) float f32x16;
typedef __attribute__((ext_vector_type(4)))  float f32x4;

#define N_NODES 16384
#define MFMA3(ACC, A, B) \
    ACC = __builtin_amdgcn_mfma_f32_32x32x16_bf16(A, B, ACC, 0, 0, 0)

// Fragment layout for the B operand of mfma_f32_32x32x16_bf16:
// element (k=r, col=c) -> 1KiB units indexed by (K16 = r>>4, cblk = c>>5),
// within a unit: lane = (c&31) + 32*((r>>3)&1) holds 8 bf16 (k = ..8g..8g+7).
__device__ __forceinline__ int frag_off(int r, int c) {
    int K16  = r >> 4;
    int cblk = c >> 5;
    int g    = (r >> 3) & 1;
    int lane = (c & 31) + (g << 5);
    return ((K16 * 4 + cblk) << 9) + (lane << 3) + (r & 7);
}

// ---------------------------------------------------------------------------
// Small fp32 GEMM producer: out = A[16384][K] @ W[K][128]; epilogue splits
// each output into bf16 hi/lo and scatters into the fragment layout.
// ---------------------------------------------------------------------------
template<int K, bool FUSED>
__global__ __launch_bounds__(256)
void producer_kernel(const float* __restrict__ A,
                     const float* __restrict__ W,
                     const float* __restrict__ Wa,
                     const float* __restrict__ Wb,
                     bf16_t* __restrict__ Bh,
                     bf16_t* __restrict__ Bl)
{
    __shared__ float As[32][128];   // k-major A tile: As[k][r]
    __shared__ float Wsh[32][128];  // Wsh[k][c]
    const int t    = threadIdx.x;
    const int row0 = blockIdx.x * 128;
    const int tc   = t & 15, tr = t >> 4;   // 16x16 thread grid, 8x8 outs each

    float acc[8][8];
    #pragma unroll
    for (int i = 0; i < 8; ++i)
        #pragma unroll
        for (int j = 0; j < 8; ++j) acc[i][j] = 0.f;

    const int ra = t >> 1, ks = (t & 1) << 4;   // A staging: 16 f32/thread
    const int wk = t >> 3, wc = (t & 7) << 4;   // W staging: 16 f32/thread

    for (int k0 = 0; k0 < K; k0 += 32) {
        const float* ap = A + (size_t)(row0 + ra) * K + k0 + ks;
        float4 a0 = *(const float4*)(ap);
        float4 a1 = *(const float4*)(ap + 4);
        float4 a2 = *(const float4*)(ap + 8);
        float4 a3 = *(const float4*)(ap + 12);
        float4 w0, w1, w2, w3;
        if (!FUSED) {
            const float* wp = W + (size_t)(k0 + wk) * 128 + wc;
            w0 = *(const float4*)(wp);     w1 = *(const float4*)(wp + 4);
            w2 = *(const float4*)(wp + 8); w3 = *(const float4*)(wp + 12);
        } else {
            const float* wp = (wc < 64) ? (Wa + (size_t)(k0 + wk) * 64 + wc)
                                        : (Wb + (size_t)(k0 + wk) * 64 + (wc - 64));
            w0 = *(const float4*)(wp);     w1 = *(const float4*)(wp + 4);
            w2 = *(const float4*)(wp + 8); w3 = *(const float4*)(wp + 12);
        }
        __syncthreads();   // previous iteration's compute done before overwrite
        {
            float tmp[16] = {a0.x,a0.y,a0.z,a0.w, a1.x,a1.y,a1.z,a1.w,
                             a2.x,a2.y,a2.z,a2.w, a3.x,a3.y,a3.z,a3.w};
            #pragma unroll
            for (int j = 0; j < 16; ++j) As[ks + j][ra] = tmp[j];
            *(float4*)&Wsh[wk][wc     ] = w0;
            *(float4*)&Wsh[wk][wc +  4] = w1;
            *(float4*)&Wsh[wk][wc +  8] = w2;
            *(float4*)&Wsh[wk][wc + 12] = w3;
        }
        __syncthreads();
        #pragma unroll 4
        for (int k = 0; k < 32; ++k) {
            float av[8], wv[8];
            *(float4*)&av[0] = *(const float4*)&As[k][8 * tr];
            *(float4*)&av[4] = *(const float4*)&As[k][8 * tr + 4];
            *(float4*)&wv[0] = *(const float4*)&Wsh[k][8 * tc];
            *(float4*)&wv[4] = *(const float4*)&Wsh[k][8 * tc + 4];
            #pragma unroll
            for (int i = 0; i < 8; ++i)
                #pragma unroll
                for (int j = 0; j < 8; ++j)
                    acc[i][j] = fmaf(av[i], wv[j], acc[i][j]);
        }
    }

    #pragma unroll
    for (int i = 0; i < 8; ++i) {
        int r = row0 + 8 * tr + i;
        #pragma unroll
        for (int j = 0; j < 8; ++j) {
            int c = 8 * tc + j;
            float v = acc[i][j];
            bf16_t h = (bf16_t)v;
            bf16_t l = (bf16_t)(v - (float)h);
            int off = frag_off(r, c);
            Bh[off] = h;
            Bl[off] = l;
        }
    }
}

// ---------------------------------------------------------------------------
// Big kernel: out = act(adj @ B), M=K=16384, N=128.
// grid 256 (1 block/CU), 512 thr (8 waves = 2 row x 4 col), tile 64x128.
// Kmacro=128: LDS [2][64][128] hi+lo = 64 KB. Per-macro issue order:
//   [loadB for macro m+1 (2 sets)] [loadAdj(m+2)] [compute: B(m), 1 macro
//   old] [cvtWrite: adj(m+1), 1 macro old] [lgkmcnt(0)-only barrier]
// -> in-order vmcnt waits never drain loads issued < 1 macro ago.
// LDS swizzle: elem (r,k) at r*128 + ((k>>3 ^ (r&15))<<3) + (k&7).
// ---------------------------------------------------------------------------
struct BSet { bf16x8 h[4]; bf16x8 l[4]; };   // 32 VGPRs

template<int ACT>  // 0=none, 1=relu
__global__ __launch_bounds__(512, 2)
void adj_gemm_kernel(const float* __restrict__ adj,
                     const bf16_t* __restrict__ Bh,
                     const bf16_t* __restrict__ Bl,
                     float* __restrict__ out)
{
    __shared__ __align__(16) bf16_t AsH[2][64 * 128];
    __shared__ __align__(16) bf16_t AsL[2][64 * 128];
    const int t    = threadIdx.x;
    const int lane = t & 63;
    const int w    = t >> 6;
    const int wr   = w >> 2, wc = w & 3;     // 2x4 wave grid
    const int row0 = blockIdx.x * 64;
    const int hi32 = lane >> 5;

    // adj staging: wave w owns rows w*8..w*8+7; inst j covers rows w*8+2j
    // (lanes 0-31) and w*8+2j+1 (lanes 32-63), 128 f32 per row per macro.
    const float* aBase = adj + (size_t)(row0 + w * 8 + hi32) * 16384
                             + (lane & 31) * 4;
    int wIdx[4];
    #pragma unroll
    for (int j = 0; j < 4; ++j) {
        int row  = w * 8 + 2 * j + hi32;
        int unit = (lane & 31) >> 1;
        wIdx[j] = (row << 7) + ((unit ^ (row & 15)) << 3) + ((lane & 1) << 2);
    }

    // A-frag reads: row frow, k-slice s: k = s*16 + hi32*8
    const int frow = (wr << 5) + (lane & 31);
    int rIdx[8];
    #pragma unroll
    for (int s = 0; s < 8; ++s)
        rIdx[s] = (frow << 7) + (((2 * s + hi32) ^ (frow & 15)) << 3);

    // B frag per-thread base (bf16 elems); sub(K=64) stride = 8192 elems
    const int tb = (wc << 9) + (lane << 3);

    f32x16 acc;
    #pragma unroll
    for (int i = 0; i < 16; ++i) acc[i] = 0.f;

    f32x4 arA[4], arB[4];
    BSet E0, E1, O0, O1;

    auto loadAdj = [&](f32x4* ar, int mac) {
        const float* p = aBase + (mac << 7);
        #pragma unroll
        for (int j = 0; j < 4; ++j)
            ar[j] = __builtin_nontemporal_load((const f32x4*)(p + (size_t)j * 32768));
    };
    auto cvtWrite = [&](int buf, const f32x4* ar) {
        bf16_t* const H = buf ? &AsH[1][0] : &AsH[0][0];
        bf16_t* const L = buf ? &AsL[1][0] : &AsL[0][0];
        #pragma unroll
        for (int j = 0; j < 4; ++j) {
            bf16x4 hv, lv;
            #pragma unroll
            for (int e = 0; e < 4; ++e) {
                float v = ar[j][e];
                bf16_t h = (bf16_t)v;
                hv[e] = h;
                lv[e] = (bf16_t)(v - (float)h);
            }
            *(bf16x4*)&H[wIdx[j]] = hv;
            *(bf16x4*)&L[wIdx[j]] = lv;
        }
    };
    auto loadB = [&](BSet& S, int sub) {
        const size_t base = ((size_t)sub << 13) + tb;
        #pragma unroll
        for (int s = 0; s < 4; ++s) {
            S.h[s] = *(const bf16x8*)(Bh + base + (s << 11));
            S.l[s] = *(const bf16x8*)(Bl + base + (s << 11));
        }
    };
    auto compute = [&](int buf, const BSet& S, int sbase) {
        const bf16_t* const H = buf ? &AsH[1][0] : &AsH[0][0];
        const bf16_t* const L = buf ? &AsL[1][0] : &AsL[0][0];
        #pragma unroll
        for (int s = 0; s < 4; ++s) {
            const int id = rIdx[sbase + s];
            bf16x8 ah = *(const bf16x8*)&H[id];
            bf16x8 al = *(const bf16x8*)&L[id];
            MFMA3(acc, ah, S.h[s]);
            MFMA3(acc, ah, S.l[s]);
            MFMA3(acc, al, S.h[s]);
        }
    };

    // lgkmcnt(0)-only barrier: ds ops drained; register-dest global loads
    // stay in flight across the barrier (counted vmcnt by compiler).
#define SYNC_LDS() do { asm volatile("s_waitcnt lgkmcnt(0)" ::: "memory"); \
                        __builtin_amdgcn_s_barrier(); } while (0)

    // -------- prologue: B(0),B(1); adj(0)->arA, adj(1)->arB; stage buf0 ----
    loadB(E0, 0);
    loadB(E1, 1);
    loadAdj(arA, 0);
    loadAdj(arB, 1);
    cvtWrite(0, arA);        // cold-start wait on adj(0)
    SYNC_LDS();

    // -------- 128 macros of K=128; macro m uses buf m&1 --------
    // even macro m: compute E (B 2m,2m+1), load O (B 2m+2,2m+3), adj(m+2)->arA,
    //               stage buf1 from arB=adj(m+1).
    for (int m = 0; m < 126; m += 2) {
        loadB(O0, 2 * m + 2);
        loadB(O1, 2 * m + 3);
        loadAdj(arA, m + 2);
        compute(0, E0, 0);
        compute(0, E1, 4);
        cvtWrite(1, arB);
        SYNC_LDS();

        loadB(E0, 2 * m + 4);
        loadB(E1, 2 * m + 5);
        loadAdj(arB, m + 3);
        compute(1, O0, 0);
        compute(1, O1, 4);
        cvtWrite(0, arA);
        SYNC_LDS();
    }
    // -------- macro 126 (even): E = B(252),B(253); arB = adj(127) --------
    loadB(O0, 254);
    loadB(O1, 255);
    compute(0, E0, 0);
    compute(0, E1, 4);
    cvtWrite(1, arB);
    SYNC_LDS();
    // -------- macro 127 (odd) --------
    compute(1, O0, 0);
    compute(1, O1, 4);
#undef SYNC_LDS

    // C write: col = lane&31 (+32*wc), row = (q&3) + 8*(q>>2) + 4*(lane>>5)
    const int col = (wc << 5) + (lane & 31);
    const int rb  = row0 + (wr << 5) + (hi32 << 2);
    #pragma unroll
    for (int q = 0; q < 16; ++q) {
        int r = rb + (q & 3) + ((q >> 2) << 3);
        float v = acc[q];
        if (ACT == 1) v = fmaxf(v, 0.f);
        out[(size_t)r * 128 + col] = v;
    }
}

// ---------------------------------------------------------------------------
// Final: mean = Z@Wp + bp; out = noise*exp(min(logstd,10)) + mean
// T = [Z | logstd] as [16384][128] f32
// ---------------------------------------------------------------------------
__global__ __launch_bounds__(256)
void final_kernel(const float* __restrict__ T,
                  const float* __restrict__ Wp,
                  const float* __restrict__ bp,
                  const float* __restrict__ noise,
                  float* __restrict__ out)
{
    __shared__ float Wps[64][64];
    __shared__ float Ts[64][64];
    const int t = threadIdx.x;
    const int row0 = blockIdx.x * 64;
    {
        int k = t >> 2, c0 = (t & 3) << 4;
        #pragma unroll
        for (int i = 0; i < 4; ++i)
            *(float4*)&Wps[k][c0 + 4 * i] = *(const float4*)&Wp[(size_t)k * 64 + c0 + 4 * i];
        #pragma unroll
        for (int i = 0; i < 4; ++i)
            *(float4*)&Ts[k][c0 + 4 * i] =
                *(const float4*)&T[(size_t)(row0 + k) * 128 + c0 + 4 * i];
    }
    __syncthreads();

    const int r  = t >> 2;
    const int c0 = (t & 3) << 4;
    float acc[16];
    #pragma unroll
    for (int j = 0; j < 16; ++j) acc[j] = bp[c0 + j];
    for (int k = 0; k < 64; ++k) {
        float a = Ts[r][k];
        #pragma unroll
        for (int j = 0; j < 16; ++j) acc[j] = fmaf(a, Wps[k][c0 + j], acc[j]);
    }
    const int grow = row0 + r;
    #pragma unroll
    for (int j = 0; j < 16; ++j) {
        float ls = T[(size_t)grow * 128 + 64 + c0 + j];
        ls = fminf(ls, 10.0f);
        out[(size_t)grow * 64 + c0 + j] =
            noise[(size_t)grow * 64 + c0 + j] * __expf(ls) + acc[j];
    }
}

// ---------------------------------------------------------------------------
extern "C" void kernel_launch(void* const* d_in, const int* in_sizes, int n_in,
                              void* d_out, int out_size, void* d_ws, size_t ws_size,
                              hipStream_t stream) {
    const float* X     = (const float*)d_in[0];
    const float* adj   = (const float*)d_in[1];
    const float* W1    = (const float*)d_in[2];
    const float* Wm    = (const float*)d_in[3];
    const float* Wsv   = (const float*)d_in[4];
    const float* Wp    = (const float*)d_in[5];
    const float* bp    = (const float*)d_in[6];
    const float* noise = (const float*)d_in[7];
    float* out = (float*)d_out;

    char* ws = (char*)d_ws;
    bf16_t* Bh   = (bf16_t*)ws;                    // 4 MB  (16384*128 bf16)
    bf16_t* Bl   = (bf16_t*)(ws + (4u << 20));     // 4 MB
    float*  Htmp = (float*)(ws + (8u << 20));      // 8 MB hidden, reused as T

    // S1: B1 = fragsplit((X @ W1)^T)
    producer_kernel<256, false><<<128, 256, 0, stream>>>(X, W1, nullptr, nullptr, Bh, Bl);
    // S2: hidden = relu(adj @ XW1)
    adj_gemm_kernel<1><<<256, 512, 0, stream>>>(adj, Bh, Bl, Htmp);
    // S3: B2 = fragsplit((hidden @ [Wm|Ws])^T)
    producer_kernel<128, true><<<128, 256, 0, stream>>>(Htmp, nullptr, Wm, Wsv, Bh, Bl);
    // S4: T = adj @ HW   (cols 0-63 = Z, 64-127 = logstd_raw)
    adj_gemm_kernel<0><<<256, 512, 0, stream>>>(adj, Bh, Bl, Htmp);
    // S5: epilogue
    final_kernel<<<256, 256, 0, stream>>>(Htmp, Wp, bp, noise, out);
}

// Round 9
// 714.580 us; speedup vs baseline: 1.7768x; 1.0752x over previous
//
#include <hip/hip_runtime.h>

// ---------------------------------------------------------------------------
// VGAE encoder, MI355X. The two adj (16384x16384 f32, 1 GiB) GEMMs dominate.
// fp32 has no MFMA on CDNA4 -> split f32 into bf16 hi+lo, 3 MFMA terms
// (hi*hi + hi*lo + lo*hi), fp32 accumulate. Floor = 2 adj passes ~340us.
// R5: K=256 macro, 1KB bursts, 1 block/CU mega-pipeline.  (724us, prev best)
// R8: strict in-order-vmcnt discipline.                   (768us, flat)
// R1-R8 lesson: EVERY 1-block/CU schedule lands at ~3 TB/s adj BW (2.1-2.3x
// HBM budget per macro, invariant to granularity/depth/ordering). The
// limiter is per-CU memory parallelism, not the schedule. m97 evidence:
// multi-block TLP (3-4 blocks/CU, simple 2-barrier loop) beats every
// hand-pipelined 1-block variant.
// R9: m97-regime adj_gemm: grid 1024 (512 row-tiles x split-K 2) = 4
// blocks/CU, 256 thr / 4 waves (= 4 B col-quadrants, no B dup), M=32,
// Kmacro=256, single-buffer 32KB LDS, 1KB adj bursts, lgkm-only barriers.
// Partials P0/P1 reduced in consumers (relu fused into S3, sum into final).
// ---------------------------------------------------------------------------

typedef __bf16 bf16_t;
typedef __attribute__((ext_vector_type(4))) __bf16 bf16x4;
typedef __attribute__((ext_vector_type(8))) __bf16 bf16x8;
typedef __attribute__((ext_vector_type(16))) float f32x16;
typedef __attribute__((ext_vector_type(4)))  float f32x4;

#define N_NODES 16384
#define MFMA3(ACC, A, B) \
    ACC = __builtin_amdgcn_mfma_f32_32x32x16_bf16(A, B, ACC, 0, 0, 0)

// Fragment layout for the B operand of mfma_f32_32x32x16_bf16:
// element (k=r, col=c) -> 1KiB units indexed by (K16 = r>>4, cblk = c>>5),
// within a unit: lane = (c&31) + 32*((r>>3)&1) holds 8 bf16 (k = ..8g..8g+7).
__device__ __forceinline__ int frag_off(int r, int c) {
    int K16  = r >> 4;
    int cblk = c >> 5;
    int g    = (r >> 3) & 1;
    int lane = (c & 31) + (g << 5);
    return ((K16 * 4 + cblk) << 9) + (lane << 3) + (r & 7);
}

__device__ __forceinline__ float4 relu_add4(float4 a, float4 b) {
    float4 r;
    r.x = fmaxf(a.x + b.x, 0.f); r.y = fmaxf(a.y + b.y, 0.f);
    r.z = fmaxf(a.z + b.z, 0.f); r.w = fmaxf(a.w + b.w, 0.f);
    return r;
}

// ---------------------------------------------------------------------------
// Small fp32 GEMM producer: out = A[16384][K] @ W[K][128]; epilogue splits
// each output into bf16 hi/lo and scatters into the fragment layout.
// ADD2: A := relu(A + A2) elementwise (fused partial-reduce of the hidden).
// ---------------------------------------------------------------------------
template<int K, bool FUSED, bool ADD2>
__global__ __launch_bounds__(256)
void producer_kernel(const float* __restrict__ A,
                     const float* __restrict__ A2,
                     const float* __restrict__ W,
                     const float* __restrict__ Wa,
                     const float* __restrict__ Wb,
                     bf16_t* __restrict__ Bh,
                     bf16_t* __restrict__ Bl)
{
    __shared__ float As[32][128];   // k-major A tile: As[k][r]
    __shared__ float Wsh[32][128];  // Wsh[k][c]
    const int t    = threadIdx.x;
    const int row0 = blockIdx.x * 128;
    const int tc   = t & 15, tr = t >> 4;   // 16x16 thread grid, 8x8 outs each

    float acc[8][8];
    #pragma unroll
    for (int i = 0; i < 8; ++i)
        #pragma unroll
        for (int j = 0; j < 8; ++j) acc[i][j] = 0.f;

    const int ra = t >> 1, ks = (t & 1) << 4;   // A staging: 16 f32/thread
    const int wk = t >> 3, wc = (t & 7) << 4;   // W staging: 16 f32/thread

    for (int k0 = 0; k0 < K; k0 += 32) {
        const float* ap = A + (size_t)(row0 + ra) * K + k0 + ks;
        float4 a0 = *(const float4*)(ap);
        float4 a1 = *(const float4*)(ap + 4);
        float4 a2 = *(const float4*)(ap + 8);
        float4 a3 = *(const float4*)(ap + 12);
        if (ADD2) {
            const float* ap2 = A2 + (size_t)(row0 + ra) * K + k0 + ks;
            a0 = relu_add4(a0, *(const float4*)(ap2));
            a1 = relu_add4(a1, *(const float4*)(ap2 + 4));
            a2 = relu_add4(a2, *(const float4*)(ap2 + 8));
            a3 = relu_add4(a3, *(const float4*)(ap2 + 12));
        }
        float4 w0, w1, w2, w3;
        if (!FUSED) {
            const float* wp = W + (size_t)(k0 + wk) * 128 + wc;
            w0 = *(const float4*)(wp);     w1 = *(const float4*)(wp + 4);
            w2 = *(const float4*)(wp + 8); w3 = *(const float4*)(wp + 12);
        } else {
            const float* wp = (wc < 64) ? (Wa + (size_t)(k0 + wk) * 64 + wc)
                                        : (Wb + (size_t)(k0 + wk) * 64 + (wc - 64));
            w0 = *(const float4*)(wp);     w1 = *(const float4*)(wp + 4);
            w2 = *(const float4*)(wp + 8); w3 = *(const float4*)(wp + 12);
        }
        __syncthreads();   // previous iteration's compute done before overwrite
        {
            float tmp[16] = {a0.x,a0.y,a0.z,a0.w, a1.x,a1.y,a1.z,a1.w,
                             a2.x,a2.y,a2.z,a2.w, a3.x,a3.y,a3.z,a3.w};
            #pragma unroll
            for (int j = 0; j < 16; ++j) As[ks + j][ra] = tmp[j];
            *(float4*)&Wsh[wk][wc     ] = w0;
            *(float4*)&Wsh[wk][wc +  4] = w1;
            *(float4*)&Wsh[wk][wc +  8] = w2;
            *(float4*)&Wsh[wk][wc + 12] = w3;
        }
        __syncthreads();
        #pragma unroll 4
        for (int k = 0; k < 32; ++k) {
            float av[8], wv[8];
            *(float4*)&av[0] = *(const float4*)&As[k][8 * tr];
            *(float4*)&av[4] = *(const float4*)&As[k][8 * tr + 4];
            *(float4*)&wv[0] = *(const float4*)&Wsh[k][8 * tc];
            *(float4*)&wv[4] = *(const float4*)&Wsh[k][8 * tc + 4];
            #pragma unroll
            for (int i = 0; i < 8; ++i)
                #pragma unroll
                for (int j = 0; j < 8; ++j)
                    acc[i][j] = fmaf(av[i], wv[j], acc[i][j]);
        }
    }

    #pragma unroll
    for (int i = 0; i < 8; ++i) {
        int r = row0 + 8 * tr + i;
        #pragma unroll
        for (int j = 0; j < 8; ++j) {
            int c = 8 * tc + j;
            float v = acc[i][j];
            bf16_t h = (bf16_t)v;
            bf16_t l = (bf16_t)(v - (float)h);
            int off = frag_off(r, c);
            Bh[off] = h;
            Bl[off] = l;
        }
    }
}

// ---------------------------------------------------------------------------
// Big kernel: P_kh = adj[rows, kh-half] @ B[kh-half], M-tile 32, K-half 8192.
// grid 1024 (512 mt x 2 kh) = 4 blocks/CU, 256 thr (4 waves = 4 B
// col-quadrants, zero B dup). 32 macros of K=256; single-buffer LDS
// [32][256] hi+lo = 32KB. adj: wave w stages rows w*8..w*8+7, one 1KB
// dwordx4 burst per row. Two lgkm-only barriers per macro; latency hiding
// via the 3 other co-resident blocks (m97 regime), not deep rings.
// LDS swizzle: elem (r,k) at (r<<8) + (((k>>4) ^ (r&15))<<4) + (k&15).
// ---------------------------------------------------------------------------
struct BSet { bf16x8 h[4]; bf16x8 l[4]; };   // 32 VGPRs

__global__ __launch_bounds__(256, 4)
void adj_gemm_kernel(const float* __restrict__ adj,
                     const bf16_t* __restrict__ Bh,
                     const bf16_t* __restrict__ Bl,
                     float* __restrict__ P0,
                     float* __restrict__ P1)
{
    __shared__ __align__(16) bf16_t AsH[32 * 256];
    __shared__ __align__(16) bf16_t AsL[32 * 256];
    const int t    = threadIdx.x;
    const int lane = t & 63;
    const int w    = t >> 6;                 // wave = B col-quadrant
    const int mt   = blockIdx.x >> 1;
    const int kh   = blockIdx.x & 1;
    const int row0 = mt << 5;
    const int hi32 = lane >> 5;
    float* const outP = kh ? P1 : P0;

    // adj staging: wave w stages rows w*8+j (j=0..7), one wave-wide dwordx4
    // burst per row (64 lanes x 16B = 1KB contiguous); macro k-span 256.
    const float* aBase = adj + (size_t)(row0 + (w << 3)) * 16384
                             + (kh << 13) + (lane << 2);

    // LDS write indices: row = w*8+j, elems k = lane*4..+3, unit16 = lane>>2
    int wIdx[8];
    #pragma unroll
    for (int j = 0; j < 8; ++j) {
        int row = (w << 3) + j;
        wIdx[j] = (row << 8) + ((((lane >> 2) ^ (row & 15)) << 4)
                                + ((lane & 3) << 2));
    }

    // LDS read: row frow = lane&31, unit u = s*4+k16, elem-in-unit = hi32*8
    const int frow  = lane & 31;
    const int rbase = (frow << 8) + (hi32 << 3);
    const int rx    = frow & 15;

    // B frag per-thread base; sub (K=64) stride = 8192 elems
    const int tb   = (w << 9) + (lane << 3);
    const int sub0 = kh << 7;                // kh*128 subs

    f32x16 acc;
    #pragma unroll
    for (int i = 0; i < 16; ++i) acc[i] = 0.f;

    f32x4 ar[8];
    BSet S;

    auto loadAdj = [&](int mac) {
        const float* p = aBase + (mac << 8);
        #pragma unroll
        for (int j = 0; j < 8; ++j)
            ar[j] = __builtin_nontemporal_load((const f32x4*)(p + (size_t)j * 16384));
    };
    auto cvtWrite = [&]() {
        #pragma unroll
        for (int j = 0; j < 8; ++j) {
            bf16x4 hv, lv;
            #pragma unroll
            for (int e = 0; e < 4; ++e) {
                float v = ar[j][e];
                bf16_t h = (bf16_t)v;
                hv[e] = h;
                lv[e] = (bf16_t)(v - (float)h);
            }
            *(bf16x4*)&AsH[wIdx[j]] = hv;
            *(bf16x4*)&AsL[wIdx[j]] = lv;
        }
    };
    auto loadB = [&](int sub) {
        const size_t base = ((size_t)sub << 13) + tb;
        #pragma unroll
        for (int s = 0; s < 4; ++s) {
            S.h[s] = *(const bf16x8*)(Bh + base + (s << 11));
            S.l[s] = *(const bf16x8*)(Bl + base + (s << 11));
        }
    };
    auto computeS = [&](int s) {
        #pragma unroll
        for (int k16 = 0; k16 < 4; ++k16) {
            const int u  = (s << 2) + k16;
            const int id = rbase + ((u ^ rx) << 4);
            bf16x8 ah = *(const bf16x8*)&AsH[id];
            bf16x8 al = *(const bf16x8*)&AsL[id];
            MFMA3(acc, ah, S.h[k16]);
            MFMA3(acc, ah, S.l[k16]);
            MFMA3(acc, al, S.h[k16]);
        }
    };

    // lgkm-only barrier: ds ops drained; register-dest global loads stay in
    // flight across the barrier (counted vmcnt by compiler).
#define SYNC_LDS() do { asm volatile("s_waitcnt lgkmcnt(0)" ::: "memory"); \
                        __builtin_amdgcn_s_barrier(); } while (0)

    loadAdj(0);
    for (int m = 0; m < 32; ++m) {
        cvtWrite();                          // waits ar = adj(m)
        SYNC_LDS();                          // staged tile visible
        const int sb = sub0 + (m << 2);
        loadB(sb + 0);
        if (m < 31) loadAdj(m + 1);          // in flight across the macro
        computeS(0);
        loadB(sb + 1);  computeS(1);
        loadB(sb + 2);  computeS(2);
        loadB(sb + 3);  computeS(3);
        SYNC_LDS();                          // reads done before overwrite
    }
#undef SYNC_LDS

    // C write: col = w*32 + lane&31, row = (q&3) + 8*(q>>2) + 4*hi32
    const int col = (w << 5) + (lane & 31);
    const int rb  = row0 + (hi32 << 2);
    #pragma unroll
    for (int q = 0; q < 16; ++q) {
        int r = rb + (q & 3) + ((q >> 2) << 3);
        outP[(size_t)r * 128 + col] = acc[q];
    }
}

// ---------------------------------------------------------------------------
// Final: T = T0+T1 ([16384][128], Z cols 0-63 | logstd cols 64-127);
// mean = Z@Wp + bp; out = noise*exp(min(logstd,10)) + mean
// ---------------------------------------------------------------------------
__global__ __launch_bounds__(256)
void final_kernel(const float* __restrict__ T0,
                  const float* __restrict__ T1,
                  const float* __restrict__ Wp,
                  const float* __restrict__ bp,
                  const float* __restrict__ noise,
                  float* __restrict__ out)
{
    __shared__ float Wps[64][64];
    __shared__ float Ts[64][64];
    const int t = threadIdx.x;
    const int row0 = blockIdx.x * 64;
    {
        int k = t >> 2, c0 = (t & 3) << 4;
        #pragma unroll
        for (int i = 0; i < 4; ++i)
            *(float4*)&Wps[k][c0 + 4 * i] = *(const float4*)&Wp[(size_t)k * 64 + c0 + 4 * i];
        #pragma unroll
        for (int i = 0; i < 4; ++i) {
            float4 z0 = *(const float4*)&T0[(size_t)(row0 + k) * 128 + c0 + 4 * i];
            float4 z1 = *(const float4*)&T1[(size_t)(row0 + k) * 128 + c0 + 4 * i];
            float4 zs; zs.x = z0.x + z1.x; zs.y = z0.y + z1.y;
            zs.z = z0.z + z1.z; zs.w = z0.w + z1.w;
            *(float4*)&Ts[k][c0 + 4 * i] = zs;
        }
    }
    __syncthreads();

    const int r  = t >> 2;
    const int c0 = (t & 3) << 4;
    float acc[16];
    #pragma unroll
    for (int j = 0; j < 16; ++j) acc[j] = bp[c0 + j];
    for (int k = 0; k < 64; ++k) {
        float a = Ts[r][k];
        #pragma unroll
        for (int j = 0; j < 16; ++j) acc[j] = fmaf(a, Wps[k][c0 + j], acc[j]);
    }
    const int grow = row0 + r;
    #pragma unroll
    for (int j = 0; j < 16; ++j) {
        size_t li = (size_t)grow * 128 + 64 + c0 + j;
        float ls = T0[li] + T1[li];
        ls = fminf(ls, 10.0f);
        out[(size_t)grow * 64 + c0 + j] =
            noise[(size_t)grow * 64 + c0 + j] * __expf(ls) + acc[j];
    }
}

// ---------------------------------------------------------------------------
extern "C" void kernel_launch(void* const* d_in, const int* in_sizes, int n_in,
                              void* d_out, int out_size, void* d_ws, size_t ws_size,
                              hipStream_t stream) {
    const float* X     = (const float*)d_in[0];
    const float* adj   = (const float*)d_in[1];
    const float* W1    = (const float*)d_in[2];
    const float* Wm    = (const float*)d_in[3];
    const float* Wsv   = (const float*)d_in[4];
    const float* Wp    = (const float*)d_in[5];
    const float* bp    = (const float*)d_in[6];
    const float* noise = (const float*)d_in[7];
    float* out = (float*)d_out;

    char* ws = (char*)d_ws;
    bf16_t* Bh = (bf16_t*)ws;                     // 4 MB
    bf16_t* Bl = (bf16_t*)(ws + (4u << 20));      // 4 MB
    float*  P0 = (float*)(ws + (8u << 20));       // 8 MB partial (kh=0)
    float*  P1 = (float*)(ws + (16u << 20));      // 8 MB partial (kh=1)

    // S1: B1 = fragsplit((X @ W1)^T)
    producer_kernel<256, false, false><<<128, 256, 0, stream>>>(
        X, nullptr, W1, nullptr, nullptr, Bh, Bl);
    // S2: hidden partials: P_kh = adj[:, kh-half] @ B1[kh-half]
    adj_gemm_kernel<<<1024, 256, 0, stream>>>(adj, Bh, Bl, P0, P1);
    // S3: B2 = fragsplit((relu(P0+P1) @ [Wm|Ws])^T)   (reduce+relu fused)
    producer_kernel<128, true, true><<<128, 256, 0, stream>>>(
        P0, P1, nullptr, Wm, Wsv, Bh, Bl);
    // S4: T partials
    adj_gemm_kernel<<<1024, 256, 0, stream>>>(adj, Bh, Bl, P0, P1);
    // S5: epilogue (T = P0+P1 summed on the fly)
    final_kernel<<<256, 256, 0, stream>>>(P0, P1, Wp, bp, noise, out);
}